// Round 15
// baseline (4263.107 us; speedup 1.0000x reference)
//
#include <hip/hip_runtime.h>

// LSTM: B=64, S=512, I=H=O=1024.  bf16 MFMA, fp32 accum.
// R15 = R14 producer/consumer CU split + first-touch h RING (513 slots) with
// PLAIN CACHED consumer h loads (L2-shared per XCD, no fence needed: each
// slot is written exactly once). xT intermediate dropped to fit ws: factories
// read fp32 x directly and convert inline. h stores sc0 sc1 nt (write-through
// no-allocate) so no stale clean L2 copies can exist.
//  - Blocks 0..127 "consumers": 4 h-waves, delegated flag polls, depth-2
//    pipelined CACHED h loads, LDS W_h fragment-linear, shfl_xor gates,
//    coalesced nt stores, last-drainer flag. No x-work, no loop barriers.
//  - Blocks 128..255 "factories": x-projection for pair block, 8 steps ahead,
//    into bf16 ring (sc0sc1); paced by consumer's h-flag.
// Fallback (ws < 90.9 MB): R10-style 512-thr kernel + convert_x.

typedef __bf16 bfv8 __attribute__((ext_vector_type(8)));
typedef float f32x4 __attribute__((ext_vector_type(4)));
typedef unsigned int u32v4 __attribute__((ext_vector_type(4)));

__device__ __forceinline__ unsigned short f2bf(float x) {
    union { float f; unsigned int u; } v; v.f = x;
    unsigned int r = (v.u + 0x7FFFu + ((v.u >> 16) & 1u)) >> 16;
    return (unsigned short)r;
}
__device__ __forceinline__ float bf2f(unsigned short s) {
    union { unsigned int u; float f; } v; v.u = ((unsigned int)s) << 16;
    return v.f;
}
__device__ __forceinline__ bfv8 cvt8(const float* p) {
    const float4 f0 = *reinterpret_cast<const float4*>(p);
    const float4 f1 = *reinterpret_cast<const float4*>(p + 4);
    unsigned short u[8] = {f2bf(f0.x), f2bf(f0.y), f2bf(f0.z), f2bf(f0.w),
                           f2bf(f1.x), f2bf(f1.y), f2bf(f1.z), f2bf(f1.w)};
    return *reinterpret_cast<const bfv8*>(u);
}

struct SrcPtrs { const float* p[9]; };

// Coherent (LLC-bypass) issue — used for the sc h path in the fallback.
#define ISSUE8(A, P, O0, O1, O2, O3, O4, O5, O6, O7)                         \
    asm volatile(                                                            \
        "global_load_dwordx4 %0, %8, off offset:" O0 " sc0 sc1\n\t"          \
        "global_load_dwordx4 %1, %8, off offset:" O1 " sc0 sc1\n\t"          \
        "global_load_dwordx4 %2, %8, off offset:" O2 " sc0 sc1\n\t"          \
        "global_load_dwordx4 %3, %8, off offset:" O3 " sc0 sc1\n\t"          \
        "global_load_dwordx4 %4, %8, off offset:" O4 " sc0 sc1\n\t"          \
        "global_load_dwordx4 %5, %8, off offset:" O5 " sc0 sc1\n\t"          \
        "global_load_dwordx4 %6, %8, off offset:" O6 " sc0 sc1\n\t"          \
        "global_load_dwordx4 %7, %8, off offset:" O7 " sc0 sc1"              \
        : "=&v"(A[0]), "=&v"(A[1]), "=&v"(A[2]), "=&v"(A[3]),                \
          "=&v"(A[4]), "=&v"(A[5]), "=&v"(A[6]), "=&v"(A[7])                 \
        : "v"(P)                                                             \
        : "memory")

// Plain cached issue — ring-mode h loads (first-touch lines, L2-shared).
#define ISSUE8C(A, P, O0, O1, O2, O3, O4, O5, O6, O7)                        \
    asm volatile(                                                            \
        "global_load_dwordx4 %0, %8, off offset:" O0 "\n\t"                  \
        "global_load_dwordx4 %1, %8, off offset:" O1 "\n\t"                  \
        "global_load_dwordx4 %2, %8, off offset:" O2 "\n\t"                  \
        "global_load_dwordx4 %3, %8, off offset:" O3 "\n\t"                  \
        "global_load_dwordx4 %4, %8, off offset:" O4 "\n\t"                  \
        "global_load_dwordx4 %5, %8, off offset:" O5 "\n\t"                  \
        "global_load_dwordx4 %6, %8, off offset:" O6 "\n\t"                  \
        "global_load_dwordx4 %7, %8, off offset:" O7                         \
        : "=&v"(A[0]), "=&v"(A[1]), "=&v"(A[2]), "=&v"(A[3]),                \
          "=&v"(A[4]), "=&v"(A[5]), "=&v"(A[6]), "=&v"(A[7])                 \
        : "v"(P)                                                             \
        : "memory")

#define WAIT8(N, A)                                                          \
    do {                                                                     \
        asm volatile("s_waitcnt vmcnt(" N ")"                                \
                     : "+v"(A[0]), "+v"(A[1]), "+v"(A[2]), "+v"(A[3]),       \
                       "+v"(A[4]), "+v"(A[5]), "+v"(A[6]), "+v"(A[7])        \
                     :: "memory");                                           \
        __builtin_amdgcn_sched_barrier(0);                                   \
    } while (0)

// 8 k-steps x 2 N-tiles vs fragment-linear LDS panel: lane-stride-1.
#define CONSUME8(A, IT0)                                                     \
    _Pragma("unroll")                                                        \
    for (int j = 0; j < 8; ++j) {                                            \
        _Pragma("unroll")                                                    \
        for (int n = 0; n < 2; ++n) {                                        \
            const int off = (((((IT0) + j) << 1) | n) << 10) + (lane << 4);  \
            acc[n] = __builtin_amdgcn_mfma_f32_16x16x32_bf16(                \
                A[j], *(const bfv8*)(Lw + off), acc[n], 0, 0, 0);            \
        }                                                                    \
    }

// ---------------------------------------------------------------------------
__global__ __launch_bounds__(256) void pack_weights(SrcPtrs sp,
                                                    unsigned short* __restrict__ Whp,
                                                    unsigned short* __restrict__ Wip,
                                                    unsigned short* __restrict__ Wy) {
    __shared__ float tile[64][65];
    const int z = blockIdx.z;
    const float* __restrict__ src = sp.p[z];
    const int n0 = blockIdx.x * 64, k0 = blockIdx.y * 64;
    const int tc = threadIdx.x & 63, tq = threadIdx.x >> 6;

    #pragma unroll
    for (int r = 0; r < 16; ++r) {
        const int kk = tq * 16 + r;
        tile[kk][tc] = src[(size_t)(k0 + kk) * 1024 + n0 + tc];
    }
    __syncthreads();
    #pragma unroll
    for (int r = 0; r < 16; ++r) {
        const int nl = tq * 16 + r;
        const int n = n0 + nl;
        const int k = k0 + tc;
        const unsigned short v = f2bf(tile[tc][nl]);
        if (z < 8) {
            const int g = z & 3;
            const int blk = n >> 3;
            const int c = (g << 3) | (n & 7);
            const int lanef = (c & 15) | (((k >> 3) & 3) << 4);
            const size_t off = ((size_t)((((blk << 5) | (k >> 5)) << 1) | (c >> 4)) << 9)
                             + (lanef << 3) + (k & 7);
            (z < 4 ? Whp : Wip)[off] = v;
        } else {
            Wy[(size_t)n * 1024 + k] = v;
        }
    }
}

// ---------------------------------------------------------------------------
__global__ __launch_bounds__(256) void convert_x(const float* __restrict__ x,
                                                 unsigned short* __restrict__ xT) {
    const size_t gid = (size_t)blockIdx.x * 256 + threadIdx.x;
    const int i0 = (int)(gid & 255) * 4;
    const size_t row = gid >> 8;            // dst row = t*64 + b
    const int t = (int)(row >> 6), b = (int)(row & 63);
    const float4 v = *reinterpret_cast<const float4*>(x + (((size_t)b * 512 + t) << 10) + i0);
    ushort4 o;
    o.x = f2bf(v.x); o.y = f2bf(v.y); o.z = f2bf(v.z); o.w = f2bf(v.w);
    *reinterpret_cast<ushort4*>(xT + (row << 10) + i0) = o;
}

// ---------------------------------------------------------------------------
// R15 unified producer/consumer kernel. 256 blocks x 256 thr.
// ---------------------------------------------------------------------------
__global__ __launch_bounds__(256) void lstm_pc(const float* __restrict__ x,
                                               const unsigned short* __restrict__ Whp,
                                               const unsigned short* __restrict__ Wip,
                                               unsigned short* __restrict__ hring,
                                               int* __restrict__ flg,
                                               int* __restrict__ xflg,
                                               unsigned short* __restrict__ ring) {
    __shared__ struct {
        __align__(16) unsigned char wp[65536];   // fragment-linear W panel
        __align__(16) unsigned char pad[32768];  // force 1 block/CU
        __align__(16) unsigned short hs[64][8];  // h store-coalescing tile
        int sig;
        int Lrdy[4];
    } L;
    unsigned char* Lw = L.wp;

    const int tid = threadIdx.x;
    const int w = tid >> 6;           // 0..3
    const int lane = tid & 63;
    const int lr = lane & 15;
    const int kq = lane >> 4;
    const bool isFactory = (blockIdx.x >= 128);
    const int b = isFactory ? (blockIdx.x - 128) : blockIdx.x;   // pair id

    // ---- stage panel (W_h for consumers, W_i for factories) ----
    {
        const unsigned short* src = (isFactory ? Wip : Whp) + ((size_t)b << 15);
        #pragma unroll
        for (int s = 0; s < 16; ++s) {
            const int c = s * 256 + tid;          // 16B chunk 0..4095
            *(bfv8*)(L.wp + c * 16) = *(const bfv8*)(src + c * 8);
        }
    }
    if (tid == 0) L.sig = 0;
    if (tid < 4) L.Lrdy[tid] = 0;
    __syncthreads();

    if (isFactory) {
        // ===== x-factory: reads fp32 x directly, up to 8 steps ahead =====
        const float* __restrict__ Axb =
            x + (size_t)((w << 4) + lr) * 524288 + kq * 8;
        for (int tt = 0; tt < 512; ++tt) {
            if (tt >= 8) {   // ring slot reuse: consumer finished tt-8
                const int* cf = flg + (b << 9);
                while (__hip_atomic_load(cf, __ATOMIC_RELAXED, __HIP_MEMORY_SCOPE_AGENT) < tt - 7)
                    __builtin_amdgcn_s_sleep(2);
            }
            const float* __restrict__ Ax = Axb + (size_t)tt * 1024;
            f32x4 xacc[2] = {};
            #pragma unroll 8
            for (int it = 0; it < 32; ++it) {
                const bfv8 a = cvt8(Ax + it * 32);
                #pragma unroll
                for (int n = 0; n < 2; ++n) {
                    const int off = (((it << 1) | n) << 10) + (lane << 4);
                    xacc[n] = __builtin_amdgcn_mfma_f32_16x16x32_bf16(
                        a, *(const bfv8*)(Lw + off), xacc[n], 0, 0, 0);
                }
            }
            unsigned short vv[8];
            #pragma unroll
            for (int n = 0; n < 2; ++n)
                #pragma unroll
                for (int r = 0; r < 4; ++r)
                    vv[n * 4 + r] = f2bf(xacc[n][r]);
            unsigned short* rp = ring + (((size_t)(b << 3) + (tt & 7)) * 4 + w) * 512 + lane * 8;
            asm volatile("global_store_dwordx4 %0, %1, off sc0 sc1"
                         :: "v"(rp), "v"(*(const u32v4*)vv) : "memory");
            asm volatile("s_waitcnt vmcnt(0)" ::: "memory");
            if (lane == 0) {
                const int old = atomicAdd(&L.sig, 1);
                if (old == 4 * tt + 3)
                    asm volatile("global_store_dword %0, %1, off sc0 sc1"
                                 :: "v"(xflg + (b << 9)), "v"(tt + 1) : "memory");
            }
        }
        return;
    }

    // ================= consumer: h recurrence (4 waves) =================
    float cst[4] = {0.f, 0.f, 0.f, 0.f};
    const int mw = w;
    const int hoff = ((mw << 4) + lr) * 1024 + kq * 8;

    for (int t = 0; t < 512; ++t) {
        const unsigned short* __restrict__ hin  = hring + ((size_t)t << 16);
        unsigned short* __restrict__       hout = hring + ((size_t)(t + 1) << 16);

        // xpart prefetch (factory runs ahead; poll is normally instant)
        const int* xfp = xflg + (b << 9);
        while (__hip_atomic_load(xfp, __ATOMIC_RELAXED, __HIP_MEMORY_SCOPE_AGENT) < t + 1)
            __builtin_amdgcn_s_sleep(1);
        u32v4 xp;
        {
            const unsigned short* rp =
                ring + (((size_t)(b << 3) + (t & 7)) * 4 + mw) * 512 + lane * 8;
            asm volatile("global_load_dwordx4 %0, %1, off sc0 sc1"
                         : "=v"(xp) : "v"(rp) : "memory");
        }

        // wave mw polls flag-group mw (32 flags), relays via LDS stamp
        if (t > 0) {
            const int* fp = flg + (((mw << 5) + (lane & 31)) << 9);
            for (;;) {
                const int f = __hip_atomic_load(fp, __ATOMIC_RELAXED,
                                                __HIP_MEMORY_SCOPE_AGENT);
                if (__all(f >= t)) break;
                __builtin_amdgcn_s_sleep(1);
            }
            __hip_atomic_store(&L.Lrdy[mw], t, __ATOMIC_RELAXED,
                               __HIP_MEMORY_SCOPE_WORKGROUP);
        }
        auto ldswait = [&](int g) {
            if (t == 0) return;
            while (__hip_atomic_load(&L.Lrdy[g], __ATOMIC_RELAXED,
                                     __HIP_MEMORY_SCOPE_WORKGROUP) < t) { }
            asm volatile("" ::: "memory");
        };

        // depth-2 pipelined CACHED h loads (first-touch ring slot; L2-shared)
        const unsigned short* hp = hin + hoff;
        f32x4 acc[2] = {};
        bfv8 a0[8], a1[8];
        ldswait(0);
        ISSUE8C(a0, hp, "0", "64", "128", "192", "256", "320", "384", "448");
        ldswait(1);
        ISSUE8C(a1, hp, "512", "576", "640", "704", "768", "832", "896", "960");
        WAIT8("8", a0);
        CONSUME8(a0, 0);
        ldswait(2);
        ISSUE8C(a0, hp, "1024", "1088", "1152", "1216", "1280", "1344", "1408", "1472");
        WAIT8("8", a1);
        CONSUME8(a1, 8);
        ldswait(3);
        ISSUE8C(a1, hp, "1536", "1600", "1664", "1728", "1792", "1856", "1920", "1984");
        WAIT8("8", a0);
        CONSUME8(a0, 16);
        WAIT8("0", a1);
        CONSUME8(a1, 24);

        // xpart now certainly complete; tie and unpack
        asm volatile("s_waitcnt vmcnt(0)" : "+v"(xp) :: "memory");
        __builtin_amdgcn_sched_barrier(0);
        {
            const unsigned short* xs = (const unsigned short*)&xp;
            #pragma unroll
            for (int n = 0; n < 2; ++n)
                #pragma unroll
                for (int r = 0; r < 4; ++r)
                    acc[n][r] += bf2f(xs[n * 4 + r]);
        }

        // gate pair-exchange + register-local epilogue
        const bool low = (lr & 8) == 0;
        unsigned short hsv[4];
        #pragma unroll
        for (int r = 0; r < 4; ++r) {
            const float s0 = acc[0][r], s1 = acc[1][r];
            const float x0 = __shfl_xor(s0, 8);
            const float x1 = __shfl_xor(s1, 8);
            const float pi = low ? s0 : x0;
            const float pf = low ? x0 : s0;
            const float po = low ? s1 : x1;
            const float pg = low ? x1 : s1;
            const float ig = 1.f / (1.f + __expf(-pi));
            const float fg = 1.f / (1.f + __expf(-pf));
            const float og = 1.f / (1.f + __expf(-po));
            const float gg = 1.f - 2.f / (__expf(2.f * pg) + 1.f);
            const float cn = fg * cst[r] + ig * gg;
            cst[r] = cn;
            hsv[r] = f2bf(og * (1.f - 2.f / (__expf(2.f * cn) + 1.f)));
        }

        // stage h in LDS (wave-private rows), then coalesced nt stores
        if (low) {
            #pragma unroll
            for (int r = 0; r < 4; ++r)
                L.hs[(mw << 4) + (kq << 2) + r][lr] = hsv[r];
        }
        asm volatile("s_waitcnt lgkmcnt(0)" ::: "memory");
        __builtin_amdgcn_sched_barrier(0);
        if (lane < 16) {
            const int row = (mw << 4) + lane;
            const u32v4 hv = *reinterpret_cast<const u32v4*>(&L.hs[row][0]);
            asm volatile("global_store_dwordx4 %0, %1, off sc0 sc1 nt"
                         :: "v"(hout + (size_t)row * 1024 + (b << 3)), "v"(hv)
                         : "memory");
        }
        asm volatile("s_waitcnt vmcnt(0)" ::: "memory");
        if (lane == 0) {
            const int old = atomicAdd(&L.sig, 1);
            if (old == 4 * t + 3)
                asm volatile("global_store_dword %0, %1, off sc0 sc1"
                             :: "v"(flg + (b << 9)), "v"(t + 1) : "memory");
        }
    }
}

// ---------------------------------------------------------------------------
// Fallback (R10 structure, 128 blocks x 512 thr) — used when ws is small.
// ---------------------------------------------------------------------------
__global__ __launch_bounds__(512) void lstm_fb(const unsigned short* __restrict__ xT,
                                               const unsigned short* __restrict__ Whp,
                                               const unsigned short* __restrict__ Wip,
                                               unsigned short* __restrict__ h0,
                                               unsigned short* __restrict__ h1,
                                               int* __restrict__ flg) {
    __shared__ struct {
        __align__(16) unsigned char wh[65536];
        __align__(16) unsigned char wi[65536];
        float xb[2][2][4][256];
        __align__(16) unsigned short hs[64][8];
        int sig;
    } L;
    unsigned char* Lw = L.wh;

    const int tid = threadIdx.x;
    const int w = tid >> 6;
    const int lane = tid & 63;
    const int lr = lane & 15;
    const int kq = lane >> 4;
    const int blk = blockIdx.x;
    const int mw = w & 3;
    const bool isX = (w >= 4);

    #pragma unroll
    for (int s = 0; s < 8; ++s) {
        const int c = s * 512 + tid;
        *(bfv8*)(L.wh + c * 16) = *(const bfv8*)(Whp + ((size_t)blk << 15) + c * 8);
        *(bfv8*)(L.wi + c * 16) = *(const bfv8*)(Wip + ((size_t)blk << 15) + c * 8);
    }
    if (tid == 0) L.sig = 0;
    __syncthreads();

    auto xwork = [&](int tt) {
        const unsigned short* __restrict__ Ax =
            xT + ((size_t)tt << 16) + (size_t)((mw << 4) + lr) * 1024 + kq * 8;
        f32x4 xacc[2] = {};
        #pragma unroll 8
        for (int it = 0; it < 32; ++it) {
            const bfv8 a = *reinterpret_cast<const bfv8*>(Ax + it * 32);
            #pragma unroll
            for (int n = 0; n < 2; ++n) {
                const int off = (((it << 1) | n) << 10) + (lane << 4);
                xacc[n] = __builtin_amdgcn_mfma_f32_16x16x32_bf16(
                    a, *(const bfv8*)(L.wi + off), xacc[n], 0, 0, 0);
            }
        }
        #pragma unroll
        for (int n = 0; n < 2; ++n)
            #pragma unroll
            for (int r = 0; r < 4; ++r)
                L.xb[tt & 1][n][r][(mw << 6) + lane] = xacc[n][r];
    };

    if (isX) xwork(0);
    __syncthreads();

    float cst[4] = {0.f, 0.f, 0.f, 0.f};
    const int hoff = ((mw << 4) + lr) * 1024 + kq * 8;

    for (int t = 0; t < 512; ++t) {
        const unsigned short* __restrict__ hin  = (t & 1) ? h1 : h0;
        unsigned short* __restrict__       hout = (t & 1) ? h0 : h1;

        if (!isX) {
            auto poll32 = [&](int g) {
                if (t == 0) return;
                const int* fp = flg + (((g << 5) + (lane & 31)) << 9);
                for (;;) {
                    const int f = __hip_atomic_load(fp, __ATOMIC_RELAXED,
                                                    __HIP_MEMORY_SCOPE_AGENT);
                    if (__all(f >= t)) break;
                    __builtin_amdgcn_s_sleep(1);
                }
            };
            const unsigned short* hp = hin + hoff;
            f32x4 acc[2] = {};
            bfv8 a0[8], a1[8];
            poll32(0);
            ISSUE8(a0, hp, "0", "64", "128", "192", "256", "320", "384", "448");
            poll32(1);
            ISSUE8(a1, hp, "512", "576", "640", "704", "768", "832", "896", "960");
            WAIT8("8", a0);
            CONSUME8(a0, 0);
            poll32(2);
            ISSUE8(a0, hp, "1024", "1088", "1152", "1216", "1280", "1344", "1408", "1472");
            WAIT8("8", a1);
            CONSUME8(a1, 8);
            poll32(3);
            ISSUE8(a1, hp, "1536", "1600", "1664", "1728", "1792", "1856", "1920", "1984");
            WAIT8("8", a0);
            CONSUME8(a0, 16);
            WAIT8("0", a1);
            CONSUME8(a1, 24);

            #pragma unroll
            for (int n = 0; n < 2; ++n)
                #pragma unroll
                for (int r = 0; r < 4; ++r)
                    acc[n][r] += L.xb[t & 1][n][r][(mw << 6) + lane];

            const bool low = (lr & 8) == 0;
            unsigned short hsv[4];
            #pragma unroll
            for (int r = 0; r < 4; ++r) {
                const float s0 = acc[0][r], s1 = acc[1][r];
                const float x0 = __shfl_xor(s0, 8);
                const float x1 = __shfl_xor(s1, 8);
                const float pi = low ? s0 : x0;
                const float pf = low ? x0 : s0;
                const float po = low ? s1 : x1;
                const float pg = low ? x1 : s1;
                const float ig = 1.f / (1.f + __expf(-pi));
                const float fg = 1.f / (1.f + __expf(-pf));
                const float og = 1.f / (1.f + __expf(-po));
                const float gg = 1.f - 2.f / (__expf(2.f * pg) + 1.f);
                const float cn = fg * cst[r] + ig * gg;
                cst[r] = cn;
                hsv[r] = f2bf(og * (1.f - 2.f / (__expf(2.f * cn) + 1.f)));
            }
            if (low) {
                #pragma unroll
                for (int r = 0; r < 4; ++r)
                    L.hs[(mw << 4) + (kq << 2) + r][lr] = hsv[r];
            }
            asm volatile("s_waitcnt lgkmcnt(0)" ::: "memory");
            __builtin_amdgcn_sched_barrier(0);
            if (lane < 16) {
                const int row = (mw << 4) + lane;
                const u32v4 hv = *reinterpret_cast<const u32v4*>(&L.hs[row][0]);
                asm volatile("global_store_dwordx4 %0, %1, off sc0 sc1"
                             :: "v"(hout + (size_t)row * 1024 + (blk << 3)), "v"(hv)
                             : "memory");
            }
            asm volatile("s_waitcnt vmcnt(0)" ::: "memory");
            if (lane == 0) {
                const int old = atomicAdd(&L.sig, 1);
                if (old == 4 * t + 3)
                    asm volatile("global_store_dword %0, %1, off sc0 sc1"
                                 :: "v"(flg + (blk << 9)), "v"(t + 1) : "memory");
            }
        } else {
            if (t + 1 < 512) xwork(t + 1);
        }
        __syncthreads();
    }
}

// ---------------------------------------------------------------------------
__global__ __launch_bounds__(256) void final_gemm(const unsigned short* __restrict__ h_in,
                                                  const unsigned short* __restrict__ WyT,
                                                  float* __restrict__ out) {
    const int tid = threadIdx.x;
    const int w = tid >> 6;
    const int lane = tid & 63;
    const int lr = lane & 15;
    const int kq = lane >> 4;
    const int c0 = blockIdx.x * 16;
    const int k0 = w * 256;

    f32x4 acc[4] = {};
    #pragma unroll 2
    for (int it = 0; it < 8; ++it) {
        const int k = k0 + it * 32 + kq * 8;
        const bfv8 bfr = *reinterpret_cast<const bfv8*>(WyT + (size_t)(c0 + lr) * 1024 + k);
        #pragma unroll
        for (int m = 0; m < 4; ++m) {
            const bfv8 a = *reinterpret_cast<const bfv8*>(h_in + (size_t)(m * 16 + lr) * 1024 + k);
            acc[m] = __builtin_amdgcn_mfma_f32_16x16x32_bf16(a, bfr, acc[m], 0, 0, 0);
        }
    }
    __shared__ float red[4][64][17];
    #pragma unroll
    for (int m = 0; m < 4; ++m)
        #pragma unroll
        for (int r = 0; r < 4; ++r)
            red[w][m * 16 + kq * 4 + r][lr] = acc[m][r];
    __syncthreads();
    #pragma unroll
    for (int u = 0; u < 4; ++u) {
        const int item = u * 256 + tid;
        const int b = item >> 4;
        const int jr = item & 15;
        const float s = red[0][b][jr] + red[1][b][jr] + red[2][b][jr] + red[3][b][jr];
        out[b * 1024 + c0 + jr] = s;
    }
}

// ---------------------------------------------------------------------------
extern "C" void kernel_launch(void* const* d_in, const int* in_sizes, int n_in,
                              void* d_out, int out_size, void* d_ws, size_t ws_size,
                              hipStream_t stream) {
    const float* x = (const float*)d_in[0];
    SrcPtrs sp;
    sp.p[0] = (const float*)d_in[1]; // W_hi
    sp.p[1] = (const float*)d_in[3]; // W_hf
    sp.p[2] = (const float*)d_in[5]; // W_ho
    sp.p[3] = (const float*)d_in[7]; // W_hg
    sp.p[4] = (const float*)d_in[2]; // W_ii
    sp.p[5] = (const float*)d_in[4]; // W_if
    sp.p[6] = (const float*)d_in[6]; // W_io
    sp.p[7] = (const float*)d_in[8]; // W_ig
    sp.p[8] = (const float*)d_in[9]; // W_y

    char* ws = (char*)d_ws;
    unsigned short* Whp = (unsigned short*)(ws + 0);          //  8 MB
    unsigned short* Wip = (unsigned short*)(ws + 8388608);    //  8 MB
    unsigned short* Wy  = (unsigned short*)(ws + 16777216);   //  2 MB -> 18874368

    pack_weights<<<dim3(16, 16, 9), 256, 0, stream>>>(sp, Whp, Wip, Wy);

    const bool split = ws_size >= 90832896ull;
    if (split) {
        // main layout: flags/rings right after Wy, then the 513-slot h ring
        int*            flg   = (int*)(ws + 18874368);             // 256 KB
        int*            xflg  = (int*)(ws + 19136512);             // 256 KB
        unsigned short* ring  = (unsigned short*)(ws + 19398656);  // 4 MB
        unsigned short* hring = (unsigned short*)(ws + 23592960);  // 513*128 KB

        hipMemsetAsync(hring, 0, 131072, stream);   // slot 0 = h_{-1} = 0
        hipMemsetAsync(flg, 0, 262144, stream);
        hipMemsetAsync(xflg, 0, 262144, stream);

        lstm_pc<<<256, 256, 0, stream>>>(x, Whp, Wip, hring, flg, xflg, ring);
        final_gemm<<<64, 256, 0, stream>>>(hring + ((size_t)512 << 16), Wy, (float*)d_out);
    } else {
        // fallback layout (R10-style)
        unsigned short* xT = (unsigned short*)(ws + 18874368);   // 64 MB
        unsigned short* h0 = (unsigned short*)(ws + 85983232);   // 128 KB
        unsigned short* h1 = (unsigned short*)(ws + 86114304);   // 128 KB
        int*            flg = (int*)(ws + 86245376);             // 256 KB

        convert_x<<<32768, 256, 0, stream>>>(x, xT);
        hipMemsetAsync(h0, 0, 131072, stream);
        hipMemsetAsync(flg, 0, 262144, stream);

        lstm_fb<<<128, 512, 0, stream>>>(xT, Whp, Wip, h0, h1, flg);
        final_gemm<<<64, 256, 0, stream>>>(h0, Wy, (float*)d_out);
    }
}

// Round 16
// 3703.572 us; speedup vs baseline: 1.1511x; 1.1511x over previous
//
#include <hip/hip_runtime.h>

// LSTM: B=64, S=512, I=H=O=1024.  bf16 MFMA, fp32 accum.
// R16 = R14 producer/consumer CU split + first-touch cached h-ring, with the
// 513-slot h ring OVERLAID on consumed xT slabs (h slot s >= 10 -> xT slab
// s-10; flag algebra proves no factory still needs that slab). Factories
// read xT via pipelined sc0sc1 loads (xT lines never enter L2 -> lines stay
// pristine for their later life as h slots). Consumers read h with PLAIN
// CACHED loads: first block per XCD fills L2 from LLC, other 15 hit L2.
// h stores sc0 sc1 nt (write-through, no-allocate). Mechanism validated by
// R15's passing absmax.
//  - Blocks 0..127 "consumers": 4 h-waves, delegated flag polls, depth-2
//    pipelined cached h loads, LDS W_h fragment-linear, shfl_xor gates,
//    coalesced nt stores, last-drainer flag. No x-work, no loop barriers.
//  - Blocks 128..255 "factories": x-projection for pair block, <=4 steps
//    ahead, pipelined sc xT loads, bf16 xpart ring (2 MB, depth 4).
// ws footprint 89.9 MB < 90.96 MB (proven available in R14).

typedef __bf16 bfv8 __attribute__((ext_vector_type(8)));
typedef float f32x4 __attribute__((ext_vector_type(4)));
typedef unsigned int u32v4 __attribute__((ext_vector_type(4)));

__device__ __forceinline__ unsigned short f2bf(float x) {
    union { float f; unsigned int u; } v; v.f = x;
    unsigned int r = (v.u + 0x7FFFu + ((v.u >> 16) & 1u)) >> 16;
    return (unsigned short)r;
}
__device__ __forceinline__ float bf2f(unsigned short s) {
    union { unsigned int u; float f; } v; v.u = ((unsigned int)s) << 16;
    return v.f;
}

struct SrcPtrs { const float* p[9]; };

// Coherent (LLC-direct, no L2 fill) issue — factory xT loads.
#define ISSUE8(A, P, O0, O1, O2, O3, O4, O5, O6, O7)                         \
    asm volatile(                                                            \
        "global_load_dwordx4 %0, %8, off offset:" O0 " sc0 sc1\n\t"          \
        "global_load_dwordx4 %1, %8, off offset:" O1 " sc0 sc1\n\t"          \
        "global_load_dwordx4 %2, %8, off offset:" O2 " sc0 sc1\n\t"          \
        "global_load_dwordx4 %3, %8, off offset:" O3 " sc0 sc1\n\t"          \
        "global_load_dwordx4 %4, %8, off offset:" O4 " sc0 sc1\n\t"          \
        "global_load_dwordx4 %5, %8, off offset:" O5 " sc0 sc1\n\t"          \
        "global_load_dwordx4 %6, %8, off offset:" O6 " sc0 sc1\n\t"          \
        "global_load_dwordx4 %7, %8, off offset:" O7 " sc0 sc1"              \
        : "=&v"(A[0]), "=&v"(A[1]), "=&v"(A[2]), "=&v"(A[3]),                \
          "=&v"(A[4]), "=&v"(A[5]), "=&v"(A[6]), "=&v"(A[7])                 \
        : "v"(P)                                                             \
        : "memory")

// Plain cached issue — consumer h loads (first-touch ring lines, L2-shared).
#define ISSUE8C(A, P, O0, O1, O2, O3, O4, O5, O6, O7)                        \
    asm volatile(                                                            \
        "global_load_dwordx4 %0, %8, off offset:" O0 "\n\t"                  \
        "global_load_dwordx4 %1, %8, off offset:" O1 "\n\t"                  \
        "global_load_dwordx4 %2, %8, off offset:" O2 "\n\t"                  \
        "global_load_dwordx4 %3, %8, off offset:" O3 "\n\t"                  \
        "global_load_dwordx4 %4, %8, off offset:" O4 "\n\t"                  \
        "global_load_dwordx4 %5, %8, off offset:" O5 "\n\t"                  \
        "global_load_dwordx4 %6, %8, off offset:" O6 "\n\t"                  \
        "global_load_dwordx4 %7, %8, off offset:" O7                         \
        : "=&v"(A[0]), "=&v"(A[1]), "=&v"(A[2]), "=&v"(A[3]),                \
          "=&v"(A[4]), "=&v"(A[5]), "=&v"(A[6]), "=&v"(A[7])                 \
        : "v"(P)                                                             \
        : "memory")

#define WAIT8(N, A)                                                          \
    do {                                                                     \
        asm volatile("s_waitcnt vmcnt(" N ")"                                \
                     : "+v"(A[0]), "+v"(A[1]), "+v"(A[2]), "+v"(A[3]),       \
                       "+v"(A[4]), "+v"(A[5]), "+v"(A[6]), "+v"(A[7])        \
                     :: "memory");                                           \
        __builtin_amdgcn_sched_barrier(0);                                   \
    } while (0)

// 8 k-steps x 2 N-tiles vs fragment-linear LDS panel: lane-stride-1.
#define CONSUME8(A, IT0)                                                     \
    _Pragma("unroll")                                                        \
    for (int j = 0; j < 8; ++j) {                                            \
        _Pragma("unroll")                                                    \
        for (int n = 0; n < 2; ++n) {                                        \
            const int off = (((((IT0) + j) << 1) | n) << 10) + (lane << 4);  \
            acc[n] = __builtin_amdgcn_mfma_f32_16x16x32_bf16(                \
                A[j], *(const bfv8*)(Lw + off), acc[n], 0, 0, 0);            \
        }                                                                    \
    }

// ---------------------------------------------------------------------------
__global__ __launch_bounds__(256) void pack_weights(SrcPtrs sp,
                                                    unsigned short* __restrict__ Whp,
                                                    unsigned short* __restrict__ Wip,
                                                    unsigned short* __restrict__ Wy) {
    __shared__ float tile[64][65];
    const int z = blockIdx.z;
    const float* __restrict__ src = sp.p[z];
    const int n0 = blockIdx.x * 64, k0 = blockIdx.y * 64;
    const int tc = threadIdx.x & 63, tq = threadIdx.x >> 6;

    #pragma unroll
    for (int r = 0; r < 16; ++r) {
        const int kk = tq * 16 + r;
        tile[kk][tc] = src[(size_t)(k0 + kk) * 1024 + n0 + tc];
    }
    __syncthreads();
    #pragma unroll
    for (int r = 0; r < 16; ++r) {
        const int nl = tq * 16 + r;
        const int n = n0 + nl;
        const int k = k0 + tc;
        const unsigned short v = f2bf(tile[tc][nl]);
        if (z < 8) {
            const int g = z & 3;
            const int blk = n >> 3;
            const int c = (g << 3) | (n & 7);
            const int lanef = (c & 15) | (((k >> 3) & 3) << 4);
            const size_t off = ((size_t)((((blk << 5) | (k >> 5)) << 1) | (c >> 4)) << 9)
                             + (lanef << 3) + (k & 7);
            (z < 4 ? Whp : Wip)[off] = v;
        } else {
            Wy[(size_t)n * 1024 + k] = v;
        }
    }
}

// ---------------------------------------------------------------------------
__global__ __launch_bounds__(256) void convert_x(const float* __restrict__ x,
                                                 unsigned short* __restrict__ xT) {
    const size_t gid = (size_t)blockIdx.x * 256 + threadIdx.x;
    const int i0 = (int)(gid & 255) * 4;
    const size_t row = gid >> 8;            // dst row = t*64 + b
    const int t = (int)(row >> 6), b = (int)(row & 63);
    const float4 v = *reinterpret_cast<const float4*>(x + (((size_t)b * 512 + t) << 10) + i0);
    ushort4 o;
    o.x = f2bf(v.x); o.y = f2bf(v.y); o.z = f2bf(v.z); o.w = f2bf(v.w);
    *reinterpret_cast<ushort4*>(xT + (row << 10) + i0) = o;
}

// ---------------------------------------------------------------------------
// R16 unified producer/consumer kernel. 256 blocks x 256 thr.
// h slot s: s<10 -> hlo + s*128KB; s>=10 -> xT slab (s-10).
// ---------------------------------------------------------------------------
__global__ __launch_bounds__(256) void lstm_pc(const unsigned short* __restrict__ xT,
                                               const unsigned short* __restrict__ Whp,
                                               const unsigned short* __restrict__ Wip,
                                               unsigned short* __restrict__ hlo,
                                               int* __restrict__ flg,
                                               int* __restrict__ xflg,
                                               unsigned short* __restrict__ ring) {
    __shared__ struct {
        __align__(16) unsigned char wp[65536];   // fragment-linear W panel
        __align__(16) unsigned char pad[32768];  // force 1 block/CU
        __align__(16) unsigned short hs[64][8];  // h store-coalescing tile
        int sig;
        int Lrdy[4];
    } L;
    unsigned char* Lw = L.wp;

    const int tid = threadIdx.x;
    const int w = tid >> 6;           // 0..3
    const int lane = tid & 63;
    const int lr = lane & 15;
    const int kq = lane >> 4;
    const bool isFactory = (blockIdx.x >= 128);
    const int b = isFactory ? (blockIdx.x - 128) : blockIdx.x;   // pair id

    // ---- stage panel (W_h for consumers, W_i for factories) ----
    {
        const unsigned short* src = (isFactory ? Wip : Whp) + ((size_t)b << 15);
        #pragma unroll
        for (int s = 0; s < 16; ++s) {
            const int c = s * 256 + tid;          // 16B chunk 0..4095
            *(bfv8*)(L.wp + c * 16) = *(const bfv8*)(src + c * 8);
        }
    }
    if (tid == 0) L.sig = 0;
    if (tid < 4) L.Lrdy[tid] = 0;
    __syncthreads();

    const int roff = ((w << 4) + lr) * 1024 + kq * 8;   // row*1024 + k-sub (ushorts)

    if (isFactory) {
        // ===== x-factory: pipelined sc xT loads, <=4 steps ahead =====
        for (int tt = 0; tt < 512; ++tt) {
            if (tt >= 4) {   // ring slot reuse: consumer finished tt-4
                const int* cf = flg + (b << 9);
                while (__hip_atomic_load(cf, __ATOMIC_RELAXED, __HIP_MEMORY_SCOPE_AGENT) < tt - 3)
                    __builtin_amdgcn_s_sleep(2);
            }
            const unsigned short* Axp = xT + ((size_t)tt << 16) + roff;
            f32x4 acc[2] = {};
            bfv8 a0[8], a1[8];
            ISSUE8(a0, Axp, "0", "64", "128", "192", "256", "320", "384", "448");
            ISSUE8(a1, Axp, "512", "576", "640", "704", "768", "832", "896", "960");
            WAIT8("8", a0);
            CONSUME8(a0, 0);
            ISSUE8(a0, Axp, "1024", "1088", "1152", "1216", "1280", "1344", "1408", "1472");
            WAIT8("8", a1);
            CONSUME8(a1, 8);
            ISSUE8(a1, Axp, "1536", "1600", "1664", "1728", "1792", "1856", "1920", "1984");
            WAIT8("8", a0);
            CONSUME8(a0, 16);
            WAIT8("0", a1);
            CONSUME8(a1, 24);

            unsigned short vv[8];
            #pragma unroll
            for (int n = 0; n < 2; ++n)
                #pragma unroll
                for (int r = 0; r < 4; ++r)
                    vv[n * 4 + r] = f2bf(acc[n][r]);
            unsigned short* rp = ring + (((size_t)(b << 2) + (tt & 3)) * 4 + w) * 512 + lane * 8;
            asm volatile("global_store_dwordx4 %0, %1, off sc0 sc1"
                         :: "v"(rp), "v"(*(const u32v4*)vv) : "memory");
            asm volatile("s_waitcnt vmcnt(0)" ::: "memory");
            if (lane == 0) {
                const int old = atomicAdd(&L.sig, 1);
                if (old == 4 * tt + 3)
                    asm volatile("global_store_dword %0, %1, off sc0 sc1"
                                 :: "v"(xflg + (b << 9)), "v"(tt + 1) : "memory");
            }
        }
        return;
    }

    // ================= consumer: h recurrence (4 waves) =================
    float cst[4] = {0.f, 0.f, 0.f, 0.f};
    const int mw = w;

    for (int t = 0; t < 512; ++t) {
        const unsigned short* __restrict__ hin =
            (t < 10) ? (hlo + ((size_t)t << 16))
                     : (xT + ((size_t)(t - 10) << 16));
        unsigned short* __restrict__ hout =
            (t + 1 < 10) ? (hlo + ((size_t)(t + 1) << 16))
                         : (const_cast<unsigned short*>(xT) + ((size_t)(t + 1 - 10) << 16));

        // xpart prefetch (factory runs ahead; poll is normally instant)
        const int* xfp = xflg + (b << 9);
        while (__hip_atomic_load(xfp, __ATOMIC_RELAXED, __HIP_MEMORY_SCOPE_AGENT) < t + 1)
            __builtin_amdgcn_s_sleep(1);
        u32v4 xp;
        {
            const unsigned short* rp =
                ring + (((size_t)(b << 2) + (t & 3)) * 4 + mw) * 512 + lane * 8;
            asm volatile("global_load_dwordx4 %0, %1, off sc0 sc1"
                         : "=v"(xp) : "v"(rp) : "memory");
        }

        // wave mw polls flag-group mw (32 flags), relays via LDS stamp
        if (t > 0) {
            const int* fp = flg + (((mw << 5) + (lane & 31)) << 9);
            for (;;) {
                const int f = __hip_atomic_load(fp, __ATOMIC_RELAXED,
                                                __HIP_MEMORY_SCOPE_AGENT);
                if (__all(f >= t)) break;
                __builtin_amdgcn_s_sleep(1);
            }
            __hip_atomic_store(&L.Lrdy[mw], t, __ATOMIC_RELAXED,
                               __HIP_MEMORY_SCOPE_WORKGROUP);
        }
        auto ldswait = [&](int g) {
            if (t == 0) return;
            while (__hip_atomic_load(&L.Lrdy[g], __ATOMIC_RELAXED,
                                     __HIP_MEMORY_SCOPE_WORKGROUP) < t) { }
            asm volatile("" ::: "memory");
        };

        // depth-2 pipelined CACHED h loads (first-touch lines; L2-shared)
        const unsigned short* hp = hin + roff;
        f32x4 acc[2] = {};
        bfv8 a0[8], a1[8];
        ldswait(0);
        ISSUE8C(a0, hp, "0", "64", "128", "192", "256", "320", "384", "448");
        ldswait(1);
        ISSUE8C(a1, hp, "512", "576", "640", "704", "768", "832", "896", "960");
        WAIT8("8", a0);
        CONSUME8(a0, 0);
        ldswait(2);
        ISSUE8C(a0, hp, "1024", "1088", "1152", "1216", "1280", "1344", "1408", "1472");
        WAIT8("8", a1);
        CONSUME8(a1, 8);
        ldswait(3);
        ISSUE8C(a1, hp, "1536", "1600", "1664", "1728", "1792", "1856", "1920", "1984");
        WAIT8("8", a0);
        CONSUME8(a0, 16);
        WAIT8("0", a1);
        CONSUME8(a1, 24);

        // xpart now certainly complete; tie and unpack
        asm volatile("s_waitcnt vmcnt(0)" : "+v"(xp) :: "memory");
        __builtin_amdgcn_sched_barrier(0);
        {
            const unsigned short* xs = (const unsigned short*)&xp;
            #pragma unroll
            for (int n = 0; n < 2; ++n)
                #pragma unroll
                for (int r = 0; r < 4; ++r)
                    acc[n][r] += bf2f(xs[n * 4 + r]);
        }

        // gate pair-exchange + register-local epilogue
        const bool low = (lr & 8) == 0;
        unsigned short hsv[4];
        #pragma unroll
        for (int r = 0; r < 4; ++r) {
            const float s0 = acc[0][r], s1 = acc[1][r];
            const float x0 = __shfl_xor(s0, 8);
            const float x1 = __shfl_xor(s1, 8);
            const float pi = low ? s0 : x0;
            const float pf = low ? x0 : s0;
            const float po = low ? s1 : x1;
            const float pg = low ? x1 : s1;
            const float ig = 1.f / (1.f + __expf(-pi));
            const float fg = 1.f / (1.f + __expf(-pf));
            const float og = 1.f / (1.f + __expf(-po));
            const float gg = 1.f - 2.f / (__expf(2.f * pg) + 1.f);
            const float cn = fg * cst[r] + ig * gg;
            cst[r] = cn;
            hsv[r] = f2bf(og * (1.f - 2.f / (__expf(2.f * cn) + 1.f)));
        }

        // stage h in LDS (wave-private rows), then coalesced nt stores
        if (low) {
            #pragma unroll
            for (int r = 0; r < 4; ++r)
                L.hs[(mw << 4) + (kq << 2) + r][lr] = hsv[r];
        }
        asm volatile("s_waitcnt lgkmcnt(0)" ::: "memory");
        __builtin_amdgcn_sched_barrier(0);
        if (lane < 16) {
            const int row = (mw << 4) + lane;
            const u32v4 hv = *reinterpret_cast<const u32v4*>(&L.hs[row][0]);
            asm volatile("global_store_dwordx4 %0, %1, off sc0 sc1 nt"
                         :: "v"(hout + (size_t)row * 1024 + (b << 3)), "v"(hv)
                         : "memory");
        }
        asm volatile("s_waitcnt vmcnt(0)" ::: "memory");
        if (lane == 0) {
            const int old = atomicAdd(&L.sig, 1);
            if (old == 4 * t + 3)
                asm volatile("global_store_dword %0, %1, off sc0 sc1"
                             :: "v"(flg + (b << 9)), "v"(t + 1) : "memory");
        }
    }
}

// ---------------------------------------------------------------------------
__global__ __launch_bounds__(256) void final_gemm(const unsigned short* __restrict__ h_in,
                                                  const unsigned short* __restrict__ WyT,
                                                  float* __restrict__ out) {
    const int tid = threadIdx.x;
    const int w = tid >> 6;
    const int lane = tid & 63;
    const int lr = lane & 15;
    const int kq = lane >> 4;
    const int c0 = blockIdx.x * 16;
    const int k0 = w * 256;

    f32x4 acc[4] = {};
    #pragma unroll 2
    for (int it = 0; it < 8; ++it) {
        const int k = k0 + it * 32 + kq * 8;
        const bfv8 bfr = *reinterpret_cast<const bfv8*>(WyT + (size_t)(c0 + lr) * 1024 + k);
        #pragma unroll
        for (int m = 0; m < 4; ++m) {
            const bfv8 a = *reinterpret_cast<const bfv8*>(h_in + (size_t)(m * 16 + lr) * 1024 + k);
            acc[m] = __builtin_amdgcn_mfma_f32_16x16x32_bf16(a, bfr, acc[m], 0, 0, 0);
        }
    }
    __shared__ float red[4][64][17];
    #pragma unroll
    for (int m = 0; m < 4; ++m)
        #pragma unroll
        for (int r = 0; r < 4; ++r)
            red[w][m * 16 + kq * 4 + r][lr] = acc[m][r];
    __syncthreads();
    #pragma unroll
    for (int u = 0; u < 4; ++u) {
        const int item = u * 256 + tid;
        const int b = item >> 4;
        const int jr = item & 15;
        const float s = red[0][b][jr] + red[1][b][jr] + red[2][b][jr] + red[3][b][jr];
        out[b * 1024 + c0 + jr] = s;
    }
}

// ---------------------------------------------------------------------------
extern "C" void kernel_launch(void* const* d_in, const int* in_sizes, int n_in,
                              void* d_out, int out_size, void* d_ws, size_t ws_size,
                              hipStream_t stream) {
    const float* x = (const float*)d_in[0];
    SrcPtrs sp;
    sp.p[0] = (const float*)d_in[1]; // W_hi
    sp.p[1] = (const float*)d_in[3]; // W_hf
    sp.p[2] = (const float*)d_in[5]; // W_ho
    sp.p[3] = (const float*)d_in[7]; // W_hg
    sp.p[4] = (const float*)d_in[2]; // W_ii
    sp.p[5] = (const float*)d_in[4]; // W_if
    sp.p[6] = (const float*)d_in[6]; // W_io
    sp.p[7] = (const float*)d_in[8]; // W_ig
    sp.p[8] = (const float*)d_in[9]; // W_y

    char* ws = (char*)d_ws;
    unsigned short* Whp  = (unsigned short*)(ws + 0);          //  8 MB
    unsigned short* Wip  = (unsigned short*)(ws + 8388608);    //  8 MB
    unsigned short* Wy   = (unsigned short*)(ws + 16777216);   //  2 MB
    unsigned short* xT   = (unsigned short*)(ws + 18874368);   // 64 MB (h slots 10..512 overlay)
    unsigned short* hlo  = (unsigned short*)(ws + 85983232);   // 10 x 128 KB (h slots 0..9)
    int*            flg  = (int*)(ws + 87293952);              // 256 KB
    int*            xflg = (int*)(ws + 87556096);              // 256 KB
    unsigned short* ring = (unsigned short*)(ws + 87818240);   // 2 MB -> 89915392

    pack_weights<<<dim3(16, 16, 9), 256, 0, stream>>>(sp, Whp, Wip, Wy);
    convert_x<<<32768, 256, 0, stream>>>(x, xT);
    hipMemsetAsync(hlo, 0, 131072, stream);   // h slot 0 = h_{-1} = 0
    hipMemsetAsync(flg, 0, 262144, stream);
    hipMemsetAsync(xflg, 0, 262144, stream);

    lstm_pc<<<256, 256, 0, stream>>>(xT, Whp, Wip, hlo, flg, xflg, ring);

    // final h = slot 512 -> xT slab 502
    final_gemm<<<64, 256, 0, stream>>>(xT + ((size_t)502 << 16), Wy, (float*)d_out);
}